// Round 2
// baseline (346.852 us; speedup 1.0000x reference)
//
#include <hip/hip_runtime.h>
#include <hip/hip_bf16.h>

// Attention block: x[16,1024,768] -> QKV -> MHA(12 heads, d=64) -> proj.
// GEMMs: 256x256-tile 8-phase schedule (HK/m201-style): BK=64, 8 waves (2Mx4N),
// 128 KiB double-buffered LDS, global_load_lds w16 staging with XOR-swizzled
// per-lane global source (linear LDS dest), counted s_waitcnt vmcnt(4) at tile
// boundaries only (never 0 in steady state), s_barrier per phase,
// s_setprio(1) around each 16-MFMA cluster, bijective XCD block swizzle.
// sched_barrier(0) after each lgkmcnt(0) per guide rule #18.
// Flash attention (R5 hybrid, unchanged).

#define EDIM 768
#define NH 12
#define HD 64
#define BB 16
#define SN 1024
#define MTOT (BB*SN)   // 16384

typedef __attribute__((ext_vector_type(8))) short short8;
typedef __attribute__((ext_vector_type(4))) short short4v;
typedef __attribute__((ext_vector_type(4))) float f32x4;
typedef unsigned short bfr;

#if defined(__HIP_DEVICE_COMPILE__)
#if !__has_builtin(__builtin_amdgcn_mfma_f32_16x16x16bf16_1k)
#error "missing __builtin_amdgcn_mfma_f32_16x16x16bf16_1k on device"
#endif
#endif

#define MFMA32(A,B,C) __builtin_amdgcn_mfma_f32_16x16x32_bf16(A,B,C,0,0,0)
#define MFMA16(A,B,C) __builtin_amdgcn_mfma_f32_16x16x16bf16_1k(A,B,C,0,0,0)

__device__ __forceinline__ bfr f2bf(float f) {
    union { float f; unsigned int u; } v; v.f = f;
    unsigned int u = v.u;
    u += 0x7FFFu + ((u >> 16) & 1u);   // RNE
    return (bfr)(u >> 16);
}
__device__ __forceinline__ bfr f2bf_fast(float f) {
    union { float f; unsigned int u; } v; v.f = f;
    return (bfr)((v.u + 0x8000u) >> 16);
}

// async global->LDS, 16 bytes per lane; lds base must be wave-uniform.
__device__ __forceinline__ void gl2lds16(const bfr* g, bfr* l) {
    __builtin_amdgcn_global_load_lds(
        (__attribute__((address_space(1))) void*)(g),
        (__attribute__((address_space(3))) void*)(l), 16, 0, 0);
}

#define BAR()   __builtin_amdgcn_s_barrier()
#define LGKM0() { asm volatile("s_waitcnt lgkmcnt(0)" ::: "memory"); \
                  __builtin_amdgcn_sched_barrier(0); }
#define VMC(n)  asm volatile("s_waitcnt vmcnt(" #n ")" ::: "memory")

// ---------------- convert fp32 -> bf16 ----------------
__global__ void k_convert(const float* __restrict__ in, bfr* __restrict__ out, int n4) {
    int i = blockIdx.x * blockDim.x + threadIdx.x;
    if (i >= n4) return;
    float4 v = ((const float4*)in)[i];
    ushort4 o;
    o.x = f2bf(v.x); o.y = f2bf(v.y); o.z = f2bf(v.z); o.w = f2bf(v.w);
    ((ushort4*)out)[i] = o;
}

// ---------------- transpose + convert: in[R][C] fp32 -> out[C][R] bf16 ----------------
__global__ void k_transpose_bf16(const float* __restrict__ in, bfr* __restrict__ out,
                                 int R, int C) {
    __shared__ float tile[32][33];
    int c0 = blockIdx.x * 32, r0 = blockIdx.y * 32;
    int tx = threadIdx.x & 31, ty = threadIdx.x >> 5;
    #pragma unroll
    for (int i = 0; i < 32; i += 8)
        tile[ty + i][tx] = in[(size_t)(r0 + ty + i) * C + c0 + tx];
    __syncthreads();
    #pragma unroll
    for (int i = 0; i < 32; i += 8)
        out[(size_t)(c0 + ty + i) * R + r0 + tx] = f2bf(tile[tx][ty + i]);
}

// ---------------- bf16 MFMA GEMM: C[M,N] = A[M,768] @ BT[N,768]^T + bias ----------------
// 256x256 tile, BK=64, 12 K-tiles. 512 threads = 8 waves, wave (wr,wc) owns a
// 128x64 output sub-tile. Per tile: 4 phases, each {ds_read subtile | stage one
// half-tile | s_barrier | lgkmcnt(0) | setprio(1) 16xMFMA setprio(0) | s_barrier}.
// Stage schedule (overwrite/consume separation >= 1 barrier, audited):
//   p0: A-top(c+1), p1: A-bot(c+1), p2: B-top(c+2), p3: B-bot(c+2)
// Boundary wait vmcnt(4): tile c+1 fully landed, the two B(c+2) halves in flight.
// LDS swizzle: granule_phys = granule_log ^ (row&7); applied on per-lane global
// source (LDS dest stays linear for global_load_lds) and on ds_read addresses.
#define QSCALE 0.18033688011112042f   // log2(e)/8
#define NT 12

template <int EPI>
__launch_bounds__(512, 2)
__global__ void k_gemm_bt(const bfr* __restrict__ A, const bfr* __restrict__ BT,
                          const float* __restrict__ bias, float* __restrict__ out,
                          bfr* __restrict__ qb, bfr* __restrict__ kb, bfr* __restrict__ vT) {
    __shared__ bfr As[2][256 * 64];   // [buf][row*64 + col], A-top rows 0..127
    __shared__ bfr Bs[2][256 * 64];

    // bijective XCD swizzle (nwg % 8 == 0: QKV 576, proj 192)
    const int gx = gridDim.x;
    const int nwg = gx * gridDim.y;
    int wgid = blockIdx.y * gx + blockIdx.x;
    wgid = (wgid & 7) * (nwg >> 3) + (wgid >> 3);
    const int n0 = (wgid % gx) * 256;
    const int m0 = (wgid / gx) * 256;

    const int t = threadIdx.x;
    const int lane = t & 63;
    const int wave = t >> 6;
    const int wr = wave >> 2;        // 0..1 -> M half (128 rows)
    const int wc = wave & 3;         // 0..3 -> N quarter (64 cols)
    const int l15 = lane & 15, quad = lane >> 4;

    // staging: thread t's 8-elem granule lands at LDS elems [t*8, t*8+8):
    // row = t>>3, physical granule = t&7, logical granule = (t&7) ^ (row&7).
    const int srow = t >> 3;
    const int sg = (t & 7) ^ (srow & 7);
    const bfr* pA = A  + (size_t)(m0 + srow) * 768 + sg * 8;
    const bfr* pB = BT + (size_t)(n0 + srow) * 768 + sg * 8;
    const int d0 = wave * 512;       // LDS elem offset for this wave's chunk (uniform)

    // read-side swizzled granule offsets (row&7 == l15&7 since rows step by 16)
    const int pg0 = (quad ^ (l15 & 7)) * 8;
    const int pg1 = ((4 + quad) ^ (l15 & 7)) * 8;
    const int arow = wr * 128 + l15;  // + mq*64 + rt*16
    const int brow = wc * 64 + l15;   // + nq*32 + ct*16

    f32x4 acc[8][4] = {};
    short8 a[4][2], b0[2][2], b1[2][2];

#define STG_A_TOP(buf, kk) { gl2lds16(pA + (kk), &As[buf][d0]); \
                             gl2lds16(pA + 49152 + (kk), &As[buf][4096 + d0]); }
#define STG_A_BOT(buf, kk) { gl2lds16(pA + 98304 + (kk), &As[buf][8192 + d0]); \
                             gl2lds16(pA + 147456 + (kk), &As[buf][12288 + d0]); }
#define STG_B_TOP(buf, kk) { gl2lds16(pB + (kk), &Bs[buf][d0]); \
                             gl2lds16(pB + 49152 + (kk), &Bs[buf][4096 + d0]); }
#define STG_B_BOT(buf, kk) { gl2lds16(pB + 98304 + (kk), &Bs[buf][8192 + d0]); \
                             gl2lds16(pB + 147456 + (kk), &Bs[buf][12288 + d0]); }

    // prologue: tile0 complete (8 loads) + B halves of tile1 (4 loads);
    // vmcnt(4) -> tile0 landed, B(1) may still fly.
    STG_A_TOP(0, 0); STG_A_BOT(0, 0); STG_B_TOP(0, 0); STG_B_BOT(0, 0);
    STG_B_TOP(1, 64); STG_B_BOT(1, 64);
    VMC(4);
    BAR();

    for (int c = 0; c < NT; ++c) {
        const int cb = c & 1;
        const bfr* Ap = &As[cb][arow * 64];
        const bfr* Bp = &Bs[cb][brow * 64];
        const int kn = (c + 1) * 64;

        // ---- phase 0: ds A[mq0]+B[nq0] | stage A-top(c+1) | mfma (mq0,nq0)
        #pragma unroll
        for (int rt = 0; rt < 4; rt++) {
            a[rt][0] = *(const short8*)(Ap + rt * 1024 + pg0);
            a[rt][1] = *(const short8*)(Ap + rt * 1024 + pg1);
        }
        #pragma unroll
        for (int ct = 0; ct < 2; ct++) {
            b0[ct][0] = *(const short8*)(Bp + ct * 1024 + pg0);
            b0[ct][1] = *(const short8*)(Bp + ct * 1024 + pg1);
        }
        if (c + 1 < NT) STG_A_TOP(cb ^ 1, kn);
        BAR(); LGKM0();
        __builtin_amdgcn_s_setprio(1);
        #pragma unroll
        for (int rt = 0; rt < 4; rt++)
            #pragma unroll
            for (int ct = 0; ct < 2; ct++) {
                acc[rt][ct] = MFMA32(a[rt][0], b0[ct][0], acc[rt][ct]);
                acc[rt][ct] = MFMA32(a[rt][1], b0[ct][1], acc[rt][ct]);
            }
        __builtin_amdgcn_s_setprio(0);
        BAR();

        // ---- phase 1: ds B[nq1] | stage A-bot(c+1) | mfma (mq0,nq1)
        #pragma unroll
        for (int ct = 0; ct < 2; ct++) {
            b1[ct][0] = *(const short8*)(Bp + 2048 + ct * 1024 + pg0);
            b1[ct][1] = *(const short8*)(Bp + 2048 + ct * 1024 + pg1);
        }
        if (c + 1 < NT) STG_A_BOT(cb ^ 1, kn);
        BAR(); LGKM0();
        __builtin_amdgcn_s_setprio(1);
        #pragma unroll
        for (int rt = 0; rt < 4; rt++)
            #pragma unroll
            for (int ct = 0; ct < 2; ct++) {
                acc[rt][2 + ct] = MFMA32(a[rt][0], b1[ct][0], acc[rt][2 + ct]);
                acc[rt][2 + ct] = MFMA32(a[rt][1], b1[ct][1], acc[rt][2 + ct]);
            }
        __builtin_amdgcn_s_setprio(0);
        BAR();

        // ---- phase 2: ds A[mq1] | stage B-top(c+2) | mfma (mq1,nq1)
        #pragma unroll
        for (int rt = 0; rt < 4; rt++) {
            a[rt][0] = *(const short8*)(Ap + 4096 + rt * 1024 + pg0);
            a[rt][1] = *(const short8*)(Ap + 4096 + rt * 1024 + pg1);
        }
        if (c + 2 < NT) STG_B_TOP(cb, kn + 64);
        BAR(); LGKM0();
        __builtin_amdgcn_s_setprio(1);
        #pragma unroll
        for (int rt = 0; rt < 4; rt++)
            #pragma unroll
            for (int ct = 0; ct < 2; ct++) {
                acc[4 + rt][2 + ct] = MFMA32(a[rt][0], b1[ct][0], acc[4 + rt][2 + ct]);
                acc[4 + rt][2 + ct] = MFMA32(a[rt][1], b1[ct][1], acc[4 + rt][2 + ct]);
            }
        __builtin_amdgcn_s_setprio(0);
        BAR();

        // ---- phase 3: stage B-bot(c+2) | mfma (mq1,nq0) | boundary vmcnt
        if (c + 2 < NT) STG_B_BOT(cb, kn + 64);
        BAR();
        __builtin_amdgcn_s_setprio(1);
        #pragma unroll
        for (int rt = 0; rt < 4; rt++)
            #pragma unroll
            for (int ct = 0; ct < 2; ct++) {
                acc[4 + rt][ct] = MFMA32(a[rt][0], b0[ct][0], acc[4 + rt][ct]);
                acc[4 + rt][ct] = MFMA32(a[rt][1], b0[ct][1], acc[4 + rt][ct]);
            }
        __builtin_amdgcn_s_setprio(0);
        if (c < NT - 2)       { VMC(4); }   // tile c+1 landed; B(c+2) in flight
        else if (c == NT - 2) { VMC(0); }   // drain A(NT-1) stages
        BAR();
    }

    #pragma unroll
    for (int r8 = 0; r8 < 8; r8++) {
        #pragma unroll
        for (int c4 = 0; c4 < 4; c4++) {
            const int col = n0 + wc * 64 + c4 * 16 + l15;
            const float bv = bias[col];
            #pragma unroll
            for (int reg = 0; reg < 4; reg++) {
                const int m = m0 + wr * 128 + r8 * 16 + quad * 4 + reg;
                float val = acc[r8][c4][reg] + bv;
                if constexpr (EPI == 0) {
                    out[(size_t)m * EDIM + col] = val;
                } else {
                    const int three = col / 768;
                    const int rem = col - three * 768;
                    const int h = rem >> 6, d = rem & 63;
                    const int b = m >> 10, n = m & 1023;
                    const size_t bh = (size_t)b * NH + h;
                    if (three == 0)      qb[(bh * SN + n) * HD + d] = f2bf(val * QSCALE);
                    else if (three == 1) kb[(bh * SN + n) * HD + d] = f2bf(val);
                    else                 vT[(bh * HD + d) * SN + n] = f2bf(val);
                }
            }
        }
    }
}

// ---------------- flash attention (R5): LDS-staged K/V, register-resident P ----------------
#define LDK 72   // 144B row stride = 9 x 16B: aligned b128, conflict-light

__launch_bounds__(256, 2)
__global__ void k_attn(const bfr* __restrict__ qb, const bfr* __restrict__ kb,
                       const bfr* __restrict__ vT, bfr* __restrict__ ao) {
    __shared__ bfr Ks[2][64 * LDK];
    __shared__ bfr Vs[2][64 * LDK];

    const int bh = blockIdx.x;            // bh fastest -> XCD L2 locality
    const int q0 = blockIdx.y * 128;
    const int t = threadIdx.x;
    const int lane = t & 63, w = t >> 6;
    const int l15 = lane & 15, quad = lane >> 4;

    const bfr* qbase = qb + (size_t)bh * SN * HD;
    const bfr* kbase = kb + (size_t)bh * SN * HD;
    const bfr* vbase = vT + (size_t)bh * HD * SN;

    short8 qf[2][2];
    #pragma unroll
    for (int qt = 0; qt < 2; qt++)
        #pragma unroll
        for (int c = 0; c < 2; c++)
            qf[qt][c] = *(const short8*)(qbase + (size_t)(q0 + w * 32 + qt * 16 + l15) * HD + c * 32 + quad * 8);

    f32x4 o_acc[2][4] = {};
    f32x4 l_acc[2] = {};
    short4v ones4;
    #pragma unroll
    for (int i = 0; i < 4; i++) ones4[i] = (short)0x3F80;

    const int srow = t >> 2;
    const int scol = (t & 3) * 16;
    const bfr* gK = kbase + (size_t)srow * HD + scol;
    const bfr* gV = vbase + (size_t)srow * SN + scol;
    const int soff = srow * LDK + scol;

    uint4 kr0, kr1, vr0, vr1;
    kr0 = *(const uint4*)(gK);      kr1 = *(const uint4*)(gK + 8);
    vr0 = *(const uint4*)(gV);      vr1 = *(const uint4*)(gV + 8);
    *(uint4*)(&Ks[0][soff]) = kr0;  *(uint4*)(&Ks[0][soff + 8]) = kr1;
    *(uint4*)(&Vs[0][soff]) = vr0;  *(uint4*)(&Vs[0][soff + 8]) = vr1;

    for (int it = 0; it < SN / 64; it++) {
        const int cur = it & 1;
        const int kv0n = (it + 1) * 64;
        if (kv0n < SN) {
            kr0 = *(const uint4*)(gK + (size_t)kv0n * HD);
            kr1 = *(const uint4*)(gK + (size_t)kv0n * HD + 8);
            vr0 = *(const uint4*)(gV + kv0n);
            vr1 = *(const uint4*)(gV + kv0n + 8);
        }
        __syncthreads();
        if (kv0n < SN) {
            *(uint4*)(&Ks[cur ^ 1][soff]) = kr0;  *(uint4*)(&Ks[cur ^ 1][soff + 8]) = kr1;
            *(uint4*)(&Vs[cur ^ 1][soff]) = vr0;  *(uint4*)(&Vs[cur ^ 1][soff + 8]) = vr1;
        }

        const bfr* Kc = &Ks[cur][0];
        const bfr* Vc = &Vs[cur][0];

        short8 kf[4][2];
        #pragma unroll
        for (int kvt = 0; kvt < 4; kvt++)
            #pragma unroll
            for (int c = 0; c < 2; c++)
                kf[kvt][c] = *(const short8*)(Kc + (kvt * 16 + l15) * LDK + c * 32 + quad * 8);
        short4v vf[4][4];
        #pragma unroll
        for (int kvt = 0; kvt < 4; kvt++)
            #pragma unroll
            for (int ct = 0; ct < 4; ct++)
                vf[kvt][ct] = *(const short4v*)(Vc + (ct * 16 + l15) * LDK + kvt * 16 + quad * 4);

        f32x4 st[4][2] = {};
        #pragma unroll
        for (int c = 0; c < 2; c++)
            #pragma unroll
            for (int kvt = 0; kvt < 4; kvt++)
                #pragma unroll
                for (int qt = 0; qt < 2; qt++)
                    st[kvt][qt] = MFMA32(kf[kvt][c], qf[qt][c], st[kvt][qt]);

        short4v pf[4][2];
        #pragma unroll
        for (int kvt = 0; kvt < 4; kvt++)
            #pragma unroll
            for (int qt = 0; qt < 2; qt++) {
                union { unsigned u[2]; short4v s; } cv;
                cv.u[0] = (unsigned)f2bf_fast(exp2f(st[kvt][qt][0]))
                        | ((unsigned)f2bf_fast(exp2f(st[kvt][qt][1])) << 16);
                cv.u[1] = (unsigned)f2bf_fast(exp2f(st[kvt][qt][2]))
                        | ((unsigned)f2bf_fast(exp2f(st[kvt][qt][3])) << 16);
                pf[kvt][qt] = cv.s;
            }

        #pragma unroll
        for (int kvt = 0; kvt < 4; kvt++)
            #pragma unroll
            for (int qt = 0; qt < 2; qt++)
                l_acc[qt] = MFMA16(pf[kvt][qt], ones4, l_acc[qt]);
        #pragma unroll
        for (int kvt = 0; kvt < 4; kvt++)
            #pragma unroll
            for (int qt = 0; qt < 2; qt++)
                #pragma unroll
                for (int ct = 0; ct < 4; ct++)
                    o_acc[qt][ct] = MFMA16(pf[kvt][qt], vf[kvt][ct], o_acc[qt][ct]);
    }

    const int bb = bh / NH, h = bh % NH;
    #pragma unroll
    for (int qt = 0; qt < 2; qt++) {
        #pragma unroll
        for (int r = 0; r < 4; r++) {
            const float inv = 1.0f / l_acc[qt][r];
            const int n = q0 + w * 32 + qt * 16 + quad * 4 + r;
            #pragma unroll
            for (int ct = 0; ct < 4; ct++) {
                const int d = ct * 16 + l15;
                ao[((size_t)bb * SN + n) * EDIM + h * HD + d] = f2bf_fast(o_acc[qt][ct][r] * inv);
            }
        }
    }
}

extern "C" void kernel_launch(void* const* d_in, const int* in_sizes, int n_in,
                              void* d_out, int out_size, void* d_ws, size_t ws_size,
                              hipStream_t stream) {
    const float* x      = (const float*)d_in[0];
    const float* w_qkv  = (const float*)d_in[1];
    const float* b_qkv  = (const float*)d_in[2];
    const float* w_proj = (const float*)d_in[3];
    const float* b_proj = (const float*)d_in[4];

    char* ws = (char*)d_ws;
    bfr* xb     = (bfr*)(ws + 0);
    bfr* wqkvT  = (bfr*)(ws + 25165824);
    bfr* wprojT = (bfr*)(ws + 28704768);
    bfr* qb     = (bfr*)(ws + 29884416);
    bfr* kb     = (bfr*)(ws + 55050240);
    bfr* vT     = (bfr*)(ws + 80216064);
    bfr* ao     = (bfr*)(ws + 105381888);

    k_convert<<<12288, 256, 0, stream>>>(x, xb, (MTOT * EDIM) / 4);
    k_transpose_bf16<<<dim3(2304 / 32, 768 / 32), 256, 0, stream>>>(w_qkv, wqkvT, 768, 2304);
    k_transpose_bf16<<<dim3(768 / 32, 768 / 32), 256, 0, stream>>>(w_proj, wprojT, 768, 768);
    k_gemm_bt<1><<<dim3(2304 / 256, MTOT / 256), 512, 0, stream>>>(
        xb, wqkvT, b_qkv, nullptr, qb, kb, vT);
    k_attn<<<dim3(BB * NH, SN / 128), 256, 0, stream>>>(qb, kb, vT, ao);
    k_gemm_bt<0><<<dim3(768 / 256, MTOT / 256), 512, 0, stream>>>(
        ao, wprojT, b_proj, (float*)d_out, nullptr, nullptr, nullptr);
}

// Round 3
// 346.544 us; speedup vs baseline: 1.0009x; 1.0009x over previous
//
#include <hip/hip_runtime.h>
#include <hip/hip_bf16.h>

// Attention block: x[16,1024,768] -> QKV -> MHA(12 heads, d=64) -> proj.
// GEMMs: 256x256 tile, BK=32, 4-deep LDS buffer rotation (128 KiB), staging
// runs 3 tiles ahead via global_load_lds w16 with counted vmcnt(8) per tile
// (never 0 in steady state) -> 8-12 KB in flight per wave ACROSS barriers.
// Conflict-free LDS granule rotation: phys = (quad + (row>>1)) & 3, inverse
// applied on per-lane global source (LDS dest linear, rule 21).
// 8 waves (2Mx4N), 2 phases/tile, s_setprio around MFMA clusters,
// bijective XCD block swizzle. Flash attention (R5 hybrid, unchanged).

#define EDIM 768
#define NH 12
#define HD 64
#define BB 16
#define SN 1024
#define MTOT (BB*SN)   // 16384

typedef __attribute__((ext_vector_type(8))) short short8;
typedef __attribute__((ext_vector_type(4))) short short4v;
typedef __attribute__((ext_vector_type(4))) float f32x4;
typedef unsigned short bfr;

#if defined(__HIP_DEVICE_COMPILE__)
#if !__has_builtin(__builtin_amdgcn_mfma_f32_16x16x16bf16_1k)
#error "missing __builtin_amdgcn_mfma_f32_16x16x16bf16_1k on device"
#endif
#endif

#define MFMA32(A,B,C) __builtin_amdgcn_mfma_f32_16x16x32_bf16(A,B,C,0,0,0)
#define MFMA16(A,B,C) __builtin_amdgcn_mfma_f32_16x16x16bf16_1k(A,B,C,0,0,0)

__device__ __forceinline__ bfr f2bf(float f) {
    union { float f; unsigned int u; } v; v.f = f;
    unsigned int u = v.u;
    u += 0x7FFFu + ((u >> 16) & 1u);   // RNE
    return (bfr)(u >> 16);
}
__device__ __forceinline__ bfr f2bf_fast(float f) {
    union { float f; unsigned int u; } v; v.f = f;
    return (bfr)((v.u + 0x8000u) >> 16);
}

// async global->LDS, 16 bytes per lane; lds base must be wave-uniform.
__device__ __forceinline__ void gl2lds16(const bfr* g, bfr* l) {
    __builtin_amdgcn_global_load_lds(
        (__attribute__((address_space(1))) void*)(g),
        (__attribute__((address_space(3))) void*)(l), 16, 0, 0);
}

#define BAR()   __builtin_amdgcn_s_barrier()
#define LGKM0() { asm volatile("s_waitcnt lgkmcnt(0)" ::: "memory"); \
                  __builtin_amdgcn_sched_barrier(0); }
#define VMC(n)  asm volatile("s_waitcnt vmcnt(" #n ")" ::: "memory")

// ---------------- convert fp32 -> bf16 ----------------
__global__ void k_convert(const float* __restrict__ in, bfr* __restrict__ out, int n4) {
    int i = blockIdx.x * blockDim.x + threadIdx.x;
    if (i >= n4) return;
    float4 v = ((const float4*)in)[i];
    ushort4 o;
    o.x = f2bf(v.x); o.y = f2bf(v.y); o.z = f2bf(v.z); o.w = f2bf(v.w);
    ((ushort4*)out)[i] = o;
}

// ---------------- transpose + convert: in[R][C] fp32 -> out[C][R] bf16 ----------------
__global__ void k_transpose_bf16(const float* __restrict__ in, bfr* __restrict__ out,
                                 int R, int C) {
    __shared__ float tile[32][33];
    int c0 = blockIdx.x * 32, r0 = blockIdx.y * 32;
    int tx = threadIdx.x & 31, ty = threadIdx.x >> 5;
    #pragma unroll
    for (int i = 0; i < 32; i += 8)
        tile[ty + i][tx] = in[(size_t)(r0 + ty + i) * C + c0 + tx];
    __syncthreads();
    #pragma unroll
    for (int i = 0; i < 32; i += 8)
        out[(size_t)(c0 + ty + i) * R + r0 + tx] = f2bf(tile[tx][ty + i]);
}

// ---------------- bf16 MFMA GEMM: C[M,N] = A[M,768] @ BT[N,768]^T + bias ----------------
// 256x256 tile, BK=32, NT=24. 512 threads = 8 waves, wave (wr,wc) owns a
// 128x64 output sub-tile. Per tile: 2 phases:
//   p0: ds a[mq0](4)+b(4) | stage A(c+3) | BAR,lgkm | 16 MFMA acc[0..3][*] | BAR
//   p1: ds a[mq1](4)      | stage B(c+3) | BAR,lgkm | 16 MFMA acc[4..7][*] | vmc | BAR
// Buffer rotation: read buf c&3, stage buf (c+3)&3 (last read in tile c-1 -> safe).
// vmcnt ladder at end of tile c: c<=NT-4 -> 8 (tiles c+2,c+3 in flight, c+1
// landed); c==NT-3 -> 4; c==NT-2 -> 0.
// Swizzle: phys_granule = (logical + (row>>1)) & 3; store-side inverse on
// per-lane GLOBAL source sg = ((t&3) - (t>>3)) & 3, LDS dest linear.
#define QSCALE 0.18033688011112042f   // log2(e)/8
#define NT 24

template <int EPI>
__launch_bounds__(512, 2)
__global__ void k_gemm_bt(const bfr* __restrict__ A, const bfr* __restrict__ BT,
                          const float* __restrict__ bias, float* __restrict__ out,
                          bfr* __restrict__ qb, bfr* __restrict__ kb, bfr* __restrict__ vT) {
    __shared__ bfr As[4][256 * 32];   // [buf][row*32 + col]
    __shared__ bfr Bs[4][256 * 32];

    // bijective XCD swizzle (nwg % 8 == 0: QKV 576, proj 192)
    const int gx = gridDim.x;
    const int nwg = gx * gridDim.y;
    int wgid = blockIdx.y * gx + blockIdx.x;
    wgid = (wgid & 7) * (nwg >> 3) + (wgid >> 3);
    const int n0 = (wgid % gx) * 256;
    const int m0 = (wgid / gx) * 256;

    const int t = threadIdx.x;
    const int lane = t & 63;
    const int wave = t >> 6;
    const int wr = wave >> 2;        // 0..1 -> M half (128 rows)
    const int wc = wave & 3;         // 0..3 -> N quarter (64 cols)
    const int l15 = lane & 15, quad = lane >> 4;

    // staging: thread t's 16B granule lands at LDS elems [t*8, t*8+8):
    // row = t>>2 (per 8 KB instruction), phys granule = t&3,
    // logical (global) granule sg = (phys - (row>>1)) & 3.
    const int srow = t >> 2;
    const int sg = ((t & 3) - (t >> 3)) & 3;
    const bfr* pA = A  + (size_t)(m0 + srow) * 768 + sg * 8;
    const bfr* pB = BT + (size_t)(n0 + srow) * 768 + sg * 8;
    const int d0 = wave * 512;       // per-wave LDS chunk base (wave-uniform)

    // read-side: phys granule = (quad + (row>>1)) & 3; (row>>1)&3 == (l15>>1)&3
    // since all row bases (wr*128, wc*64, rf*16, ct*16) are 0 mod 8.
    const int pg = ((quad + (l15 >> 1)) & 3) * 8;
    const int arow = wr * 128 + l15;  // + rf*16 (p0), +64 (p1)
    const int brow = wc * 64 + l15;   // + ct*16

    f32x4 acc[8][4] = {};
    short8 a[4], b[4];

#define STG_A(buf, kk) { gl2lds16(pA + (kk), &As[buf][d0]); \
                         gl2lds16(pA + 98304 + (kk), &As[buf][4096 + d0]); }
#define STG_B(buf, kk) { gl2lds16(pB + (kk), &Bs[buf][d0]); \
                         gl2lds16(pB + 98304 + (kk), &Bs[buf][4096 + d0]); }

    // prologue: stage tiles 0,1,2 (12 loads); vmcnt(8) -> tile0's 4 landed.
    STG_A(0, 0);  STG_B(0, 0);
    STG_A(1, 32); STG_B(1, 32);
    STG_A(2, 64); STG_B(2, 64);
    VMC(8);
    BAR();

    for (int c = 0; c < NT; ++c) {
        const int rb = c & 3;
        const int sb = (c + 3) & 3;
        const bfr* Ap = &As[rb][arow * 32];
        const bfr* Bp = &Bs[rb][brow * 32];
        const int kk = (c + 3) * 32;

        // ---- phase 0: ds a[mq0]+b | stage A(c+3) | mfma rows 0..63 of sub-tile
        #pragma unroll
        for (int rf = 0; rf < 4; rf++)
            a[rf] = *(const short8*)(Ap + rf * 512 + pg);
        #pragma unroll
        for (int ct = 0; ct < 4; ct++)
            b[ct] = *(const short8*)(Bp + ct * 512 + pg);
        if (c + 3 < NT) STG_A(sb, kk);
        BAR(); LGKM0();
        __builtin_amdgcn_s_setprio(1);
        #pragma unroll
        for (int rf = 0; rf < 4; rf++)
            #pragma unroll
            for (int ct = 0; ct < 4; ct++)
                acc[rf][ct] = MFMA32(a[rf], b[ct], acc[rf][ct]);
        __builtin_amdgcn_s_setprio(0);
        BAR();

        // ---- phase 1: ds a[mq1] | stage B(c+3) | mfma rows 64..127 | vmc ladder
        #pragma unroll
        for (int rf = 0; rf < 4; rf++)
            a[rf] = *(const short8*)(Ap + 2048 + rf * 512 + pg);
        if (c + 3 < NT) STG_B(sb, kk);
        BAR(); LGKM0();
        __builtin_amdgcn_s_setprio(1);
        #pragma unroll
        for (int rf = 0; rf < 4; rf++)
            #pragma unroll
            for (int ct = 0; ct < 4; ct++)
                acc[4 + rf][ct] = MFMA32(a[rf], b[ct], acc[4 + rf][ct]);
        __builtin_amdgcn_s_setprio(0);
        if (c <= NT - 4)      { VMC(8); }   // c+1 landed; c+2,c+3 in flight
        else if (c == NT - 3) { VMC(4); }   // only c+3(=NT-... none) -> c+2 landed
        else if (c == NT - 2) { VMC(0); }   // drain last tile
        BAR();
    }

    #pragma unroll
    for (int r8 = 0; r8 < 8; r8++) {
        #pragma unroll
        for (int c4 = 0; c4 < 4; c4++) {
            const int col = n0 + wc * 64 + c4 * 16 + l15;
            const float bv = bias[col];
            #pragma unroll
            for (int reg = 0; reg < 4; reg++) {
                const int m = m0 + wr * 128 + r8 * 16 + quad * 4 + reg;
                float val = acc[r8][c4][reg] + bv;
                if constexpr (EPI == 0) {
                    out[(size_t)m * EDIM + col] = val;
                } else {
                    const int three = col / 768;
                    const int rem = col - three * 768;
                    const int h = rem >> 6, d = rem & 63;
                    const int b = m >> 10, n = m & 1023;
                    const size_t bh = (size_t)b * NH + h;
                    if (three == 0)      qb[(bh * SN + n) * HD + d] = f2bf(val * QSCALE);
                    else if (three == 1) kb[(bh * SN + n) * HD + d] = f2bf(val);
                    else                 vT[(bh * HD + d) * SN + n] = f2bf(val);
                }
            }
        }
    }
}

// ---------------- flash attention (R5): LDS-staged K/V, register-resident P ----------------
#define LDK 72   // 144B row stride = 9 x 16B: aligned b128, conflict-light

__launch_bounds__(256, 2)
__global__ void k_attn(const bfr* __restrict__ qb, const bfr* __restrict__ kb,
                       const bfr* __restrict__ vT, bfr* __restrict__ ao) {
    __shared__ bfr Ks[2][64 * LDK];
    __shared__ bfr Vs[2][64 * LDK];

    const int bh = blockIdx.x;            // bh fastest -> XCD L2 locality
    const int q0 = blockIdx.y * 128;
    const int t = threadIdx.x;
    const int lane = t & 63, w = t >> 6;
    const int l15 = lane & 15, quad = lane >> 4;

    const bfr* qbase = qb + (size_t)bh * SN * HD;
    const bfr* kbase = kb + (size_t)bh * SN * HD;
    const bfr* vbase = vT + (size_t)bh * HD * SN;

    short8 qf[2][2];
    #pragma unroll
    for (int qt = 0; qt < 2; qt++)
        #pragma unroll
        for (int c = 0; c < 2; c++)
            qf[qt][c] = *(const short8*)(qbase + (size_t)(q0 + w * 32 + qt * 16 + l15) * HD + c * 32 + quad * 8);

    f32x4 o_acc[2][4] = {};
    f32x4 l_acc[2] = {};
    short4v ones4;
    #pragma unroll
    for (int i = 0; i < 4; i++) ones4[i] = (short)0x3F80;

    const int srow = t >> 2;
    const int scol = (t & 3) * 16;
    const bfr* gK = kbase + (size_t)srow * HD + scol;
    const bfr* gV = vbase + (size_t)srow * SN + scol;
    const int soff = srow * LDK + scol;

    uint4 kr0, kr1, vr0, vr1;
    kr0 = *(const uint4*)(gK);      kr1 = *(const uint4*)(gK + 8);
    vr0 = *(const uint4*)(gV);      vr1 = *(const uint4*)(gV + 8);
    *(uint4*)(&Ks[0][soff]) = kr0;  *(uint4*)(&Ks[0][soff + 8]) = kr1;
    *(uint4*)(&Vs[0][soff]) = vr0;  *(uint4*)(&Vs[0][soff + 8]) = vr1;

    for (int it = 0; it < SN / 64; it++) {
        const int cur = it & 1;
        const int kv0n = (it + 1) * 64;
        if (kv0n < SN) {
            kr0 = *(const uint4*)(gK + (size_t)kv0n * HD);
            kr1 = *(const uint4*)(gK + (size_t)kv0n * HD + 8);
            vr0 = *(const uint4*)(gV + kv0n);
            vr1 = *(const uint4*)(gV + kv0n + 8);
        }
        __syncthreads();
        if (kv0n < SN) {
            *(uint4*)(&Ks[cur ^ 1][soff]) = kr0;  *(uint4*)(&Ks[cur ^ 1][soff + 8]) = kr1;
            *(uint4*)(&Vs[cur ^ 1][soff]) = vr0;  *(uint4*)(&Vs[cur ^ 1][soff + 8]) = vr1;
        }

        const bfr* Kc = &Ks[cur][0];
        const bfr* Vc = &Vs[cur][0];

        short8 kf[4][2];
        #pragma unroll
        for (int kvt = 0; kvt < 4; kvt++)
            #pragma unroll
            for (int c = 0; c < 2; c++)
                kf[kvt][c] = *(const short8*)(Kc + (kvt * 16 + l15) * LDK + c * 32 + quad * 8);
        short4v vf[4][4];
        #pragma unroll
        for (int kvt = 0; kvt < 4; kvt++)
            #pragma unroll
            for (int ct = 0; ct < 4; ct++)
                vf[kvt][ct] = *(const short4v*)(Vc + (ct * 16 + l15) * LDK + kvt * 16 + quad * 4);

        f32x4 st[4][2] = {};
        #pragma unroll
        for (int c = 0; c < 2; c++)
            #pragma unroll
            for (int kvt = 0; kvt < 4; kvt++)
                #pragma unroll
                for (int qt = 0; qt < 2; qt++)
                    st[kvt][qt] = MFMA32(kf[kvt][c], qf[qt][c], st[kvt][qt]);

        short4v pf[4][2];
        #pragma unroll
        for (int kvt = 0; kvt < 4; kvt++)
            #pragma unroll
            for (int qt = 0; qt < 2; qt++) {
                union { unsigned u[2]; short4v s; } cv;
                cv.u[0] = (unsigned)f2bf_fast(exp2f(st[kvt][qt][0]))
                        | ((unsigned)f2bf_fast(exp2f(st[kvt][qt][1])) << 16);
                cv.u[1] = (unsigned)f2bf_fast(exp2f(st[kvt][qt][2]))
                        | ((unsigned)f2bf_fast(exp2f(st[kvt][qt][3])) << 16);
                pf[kvt][qt] = cv.s;
            }

        #pragma unroll
        for (int kvt = 0; kvt < 4; kvt++)
            #pragma unroll
            for (int qt = 0; qt < 2; qt++)
                l_acc[qt] = MFMA16(pf[kvt][qt], ones4, l_acc[qt]);
        #pragma unroll
        for (int kvt = 0; kvt < 4; kvt++)
            #pragma unroll
            for (int qt = 0; qt < 2; qt++)
                #pragma unroll
                for (int ct = 0; ct < 4; ct++)
                    o_acc[qt][ct] = MFMA16(pf[kvt][qt], vf[kvt][ct], o_acc[qt][ct]);
    }

    const int bb = bh / NH, h = bh % NH;
    #pragma unroll
    for (int qt = 0; qt < 2; qt++) {
        #pragma unroll
        for (int r = 0; r < 4; r++) {
            const float inv = 1.0f / l_acc[qt][r];
            const int n = q0 + w * 32 + qt * 16 + quad * 4 + r;
            #pragma unroll
            for (int ct = 0; ct < 4; ct++) {
                const int d = ct * 16 + l15;
                ao[((size_t)bb * SN + n) * EDIM + h * HD + d] = f2bf_fast(o_acc[qt][ct][r] * inv);
            }
        }
    }
}

extern "C" void kernel_launch(void* const* d_in, const int* in_sizes, int n_in,
                              void* d_out, int out_size, void* d_ws, size_t ws_size,
                              hipStream_t stream) {
    const float* x      = (const float*)d_in[0];
    const float* w_qkv  = (const float*)d_in[1];
    const float* b_qkv  = (const float*)d_in[2];
    const float* w_proj = (const float*)d_in[3];
    const float* b_proj = (const float*)d_in[4];

    char* ws = (char*)d_ws;
    bfr* xb     = (bfr*)(ws + 0);
    bfr* wqkvT  = (bfr*)(ws + 25165824);
    bfr* wprojT = (bfr*)(ws + 28704768);
    bfr* qb     = (bfr*)(ws + 29884416);
    bfr* kb     = (bfr*)(ws + 55050240);
    bfr* vT     = (bfr*)(ws + 80216064);
    bfr* ao     = (bfr*)(ws + 105381888);

    k_convert<<<12288, 256, 0, stream>>>(x, xb, (MTOT * EDIM) / 4);
    k_transpose_bf16<<<dim3(2304 / 32, 768 / 32), 256, 0, stream>>>(w_qkv, wqkvT, 768, 2304);
    k_transpose_bf16<<<dim3(768 / 32, 768 / 32), 256, 0, stream>>>(w_proj, wprojT, 768, 768);
    k_gemm_bt<1><<<dim3(2304 / 256, MTOT / 256), 512, 0, stream>>>(
        xb, wqkvT, b_qkv, nullptr, qb, kb, vT);
    k_attn<<<dim3(BB * NH, SN / 128), 256, 0, stream>>>(qb, kb, vT, ao);
    k_gemm_bt<0><<<dim3(768 / 256, MTOT / 256), 512, 0, stream>>>(
        ao, wprojT, b_proj, (float*)d_out, nullptr, nullptr, nullptr);
}